// Round 10
// baseline (165.019 us; speedup 1.0000x reference)
//
#include <hip/hip_runtime.h>
#include <hip/hip_bf16.h>

// CausalSelfAttention: B=8 T=2048 C=126 H=6 D=21
// Round 10:
//  attn: K/V software prefetch (t+4 loaded before t computed), exp2 path
//    (log2e folded into Q pre-scale), long blocks launched first.
//  pipeline: sniff kernel removed (inline per-block probe), 4 launches.
//  qkv: x staged via packed 2-column uint loads.

#define B_ 8
#define T_ 2048
#define C_ 126
#define H_ 6
#define D_ 21
#define TC_ 378    // 3*C
#define KP_ 128    // padded GEMM inner dim
#define DP_ 32     // padded head dim
#define M_ 16384   // B*T
#define QSCALE 0.31481923469333463f   // (1/sqrt(21)) * log2(e)

typedef __hip_bfloat16 bf16;
typedef __bf16 bf16_t;
typedef __bf16 bf16x8 __attribute__((ext_vector_type(8)));
typedef float f32x4 __attribute__((ext_vector_type(4)));

__device__ __forceinline__ float ldf(const bf16* p, long i) { return __bfloat162float(p[i]); }
__device__ __forceinline__ float ldf(const float* p, long i) { return p[i]; }
__device__ __forceinline__ void stf(bf16* p, long i, float v) { p[i] = __float2bfloat16(v); }
__device__ __forceinline__ void stf(float* p, long i, float v) { p[i] = v; }

// packed 2-column loader (cols 2c, 2c+1) -> uint of 2 bf16
__device__ __forceinline__ unsigned int ld2(const bf16* x, long i) {
  return *(const unsigned int*)((const unsigned short*)x + i);
}
__device__ __forceinline__ unsigned int ld2(const float* x, long i) {
  const float2 f = *(const float2*)(x + i);
  union { bf16_t b[2]; unsigned int u; } cv;
  cv.b[0] = (bf16_t)f.x; cv.b[1] = (bf16_t)f.y;
  return cv.u;
}

// ------------- inline dtype probe: wave 0 -> sflag (1 = bf16) -------------
__device__ __forceinline__ void probe_dtype(const void* x, int tid, int* sflag) {
  if (tid < 64) {
    const unsigned int w = ((const unsigned int*)x)[tid * 97 + 13];
    const unsigned int e = (w >> 7) & 0xFF;
    const bool bflike = (e >= 115 && e <= 131) || ((w & 0x7FFFu) == 0);
    const unsigned long long mask = __ballot(bflike);
    if (tid == 0) *sflag = (__popcll(mask) >= 40) ? 1 : 0;
  }
  __syncthreads();
}

// ------------- prep: WT_attn[384][128], WT_proj[128][128] -----------------
template <typename T>
__device__ __forceinline__ void prep_w_body(const T* __restrict__ wa,
                                            const T* __restrict__ wp,
                                            bf16_t* __restrict__ WTa,
                                            bf16_t* __restrict__ WTp) {
  const int stride = gridDim.x * blockDim.x;
  const int idx0 = blockIdx.x * blockDim.x + threadIdx.x;
  for (int i = idx0; i < 384 * KP_ + KP_ * KP_; i += stride) {
    if (i < 384 * KP_) {
      const int n = i >> 7, k = i & 127;
      WTa[i] = (k < C_ && n < TC_) ? (bf16_t)ldf(wa, (long)k * TC_ + n) : (bf16_t)0.f;
    } else {
      const int j = i - 384 * KP_;
      const int n = j >> 7, k = j & 127;
      WTp[j] = (k < C_ && n < C_) ? (bf16_t)ldf(wp, (long)k * C_ + n) : (bf16_t)0.f;
    }
  }
}

__global__ __launch_bounds__(256) void prep_w_kernel(
    const void* __restrict__ x, const void* __restrict__ wa,
    const void* __restrict__ wp, bf16_t* __restrict__ WTa,
    bf16_t* __restrict__ WTp) {
  __shared__ int sflag;
  probe_dtype(x, threadIdx.x, &sflag);
  if (sflag) prep_w_body<bf16>((const bf16*)wa, (const bf16*)wp, WTa, WTp);
  else       prep_w_body<float>((const float*)wa, (const float*)wp, WTa, WTp);
}

// ------------- qkv = x @ w_attn via MFMA, LDS-transposed stores -----------
#define QS_ 40   // qbuf/kbuf d-stride (80 B, 16-aligned rows)

template <typename T>
__device__ __forceinline__ void qkv_body(
    const T* __restrict__ x, const bf16_t* __restrict__ WT,
    bf16_t* __restrict__ Qb, bf16_t* __restrict__ Kb, bf16_t* __restrict__ VT,
    bf16_t* __restrict__ xs, bf16_t* __restrict__ qbuf,
    bf16_t* __restrict__ kbuf, bf16_t* __restrict__ vbuf) {
  const int m0 = blockIdx.x * 16;
  const int tid = threadIdx.x;
  // packed x staging: 16 rows x 64 uint slots (128 cols, top 2 = pad)
  for (int i = tid; i < 16 * 64; i += 256) {
    const int row = i >> 6, cp = i & 63;
    unsigned int v = 0;
    if (cp < 63) v = ld2(x, (long)(m0 + row) * C_ + 2 * cp);
    ((unsigned int*)xs)[i] = v;
  }
  // pad init: qbuf/kbuf d=21..31 zero; vbuf d=21 ones, d=22..31 zero
  for (int i = tid; i < 6 * 16 * 11; i += 256) {
    const int h = i / 176, rem = i - h * 176, t = rem / 11, d = 21 + rem % 11;
    qbuf[(h * 16 + t) * QS_ + d] = (bf16_t)0.f;
    kbuf[(h * 16 + t) * QS_ + d] = (bf16_t)0.f;
  }
  for (int i = tid; i < 6 * 11 * 16; i += 256) {
    const int h = i / 176, rem = i - h * 176, d = 21 + rem / 16, t = rem % 16;
    vbuf[(h * 32 + d) * 16 + t] = (d == 21) ? (bf16_t)1.f : (bf16_t)0.f;
  }
  __syncthreads();

  const int wv = tid >> 6, lane = tid & 63;
  const int lr = lane & 15, quad = lane >> 4;
  const bf16_t* ar = xs + lr * KP_ + quad * 8;
  const bf16x8 a0 = *(const bf16x8*)(ar);
  const bf16x8 a1 = *(const bf16x8*)(ar + 32);
  const bf16x8 a2 = *(const bf16x8*)(ar + 64);
  const bf16x8 a3 = *(const bf16x8*)(ar + 96);

  for (int nt = wv; nt < 24; nt += 4) {
    const int n0 = nt * 16;
    const bf16x8* bp = (const bf16x8*)(WT + (long)(n0 + lr) * KP_ + quad * 8);
    f32x4 acc = {0.f, 0.f, 0.f, 0.f};
    acc = __builtin_amdgcn_mfma_f32_16x16x32_bf16(a0, bp[0],  acc, 0, 0, 0);
    acc = __builtin_amdgcn_mfma_f32_16x16x32_bf16(a1, bp[4],  acc, 0, 0, 0);
    acc = __builtin_amdgcn_mfma_f32_16x16x32_bf16(a2, bp[8],  acc, 0, 0, 0);
    acc = __builtin_amdgcn_mfma_f32_16x16x32_bf16(a3, bp[12], acc, 0, 0, 0);

    const int c = n0 + lr;                 // 0..383
    if (c < TC_) {
      const int which = c / C_;
      const int cc = c - which * C_;
      const int h = cc / D_, d = cc - h * D_;
#pragma unroll
      for (int r = 0; r < 4; ++r) {
        const int t = quad * 4 + r;        // C layout: row = quad*4 + reg
        if (which == 0)
          qbuf[(h * 16 + t) * QS_ + d] = (bf16_t)(acc[r] * QSCALE);  // incl log2e
        else if (which == 1)
          kbuf[(h * 16 + t) * QS_ + d] = (bf16_t)acc[r];
        else
          vbuf[(h * 32 + d) * 16 + t] = (bf16_t)acc[r];
      }
    }
  }
  __syncthreads();

  // ---- coalesced store phase ----
  const int b = m0 >> 11, t0 = m0 & 2047;
  for (int i = tid; i < 192; i += 256) {   // Q,K: 96 rows each, 64 B
    const int j = (i < 96) ? i : i - 96;
    const int h = j >> 4, t = j & 15;
    const int4* src = (const int4*)(((i < 96) ? qbuf : kbuf) + (h * 16 + t) * QS_);
    int4* dst = (int4*)((((i < 96) ? Qb : Kb)) + ((long)(b * H_ + h) * T_ + (t0 + t)) * DP_);
    dst[0] = src[0]; dst[1] = src[1]; dst[2] = src[2]; dst[3] = src[3];
  }
  for (int i = tid; i < 192; i += 256) {   // VT: 192 rows, 32 B
    const int h = i >> 5, d = i & 31;
    const int4* src = (const int4*)(vbuf + (h * 32 + d) * 16);
    int4* dst = (int4*)(VT + ((long)(b * H_ + h) * DP_ + d) * T_ + t0);
    dst[0] = src[0]; dst[1] = src[1];
  }
}

__global__ __launch_bounds__(256) void qkv_mfma(
    const void* __restrict__ x, const bf16_t* __restrict__ WT,
    bf16_t* __restrict__ Qb, bf16_t* __restrict__ Kb, bf16_t* __restrict__ VT) {
  __shared__ __align__(16) bf16_t xs[16 * KP_];
  __shared__ __align__(16) bf16_t qbuf[6 * 16 * QS_];
  __shared__ __align__(16) bf16_t kbuf[6 * 16 * QS_];
  __shared__ __align__(16) bf16_t vbuf[6 * 32 * 16];
  __shared__ int sflag;
  probe_dtype(x, threadIdx.x, &sflag);
  if (sflag) qkv_body<bf16>((const bf16*)x, WT, Qb, Kb, VT, xs, qbuf, kbuf, vbuf);
  else       qkv_body<float>((const float*)x, WT, Qb, Kb, VT, xs, qbuf, kbuf, vbuf);
}

// ------------- MFMA causal flash attention, key-split + prefetch ----------
// grid (48, 64): x = bh (XCD-local), y -> pr = 63-y (long blocks first).
// Wave wv: key-blocks t = wv, wv+4, ... <= pr, with K/V frags for t+4
// prefetched before computing t. Q carries 1/sqrt(21)*log2e -> exp2f.
// No-max softmax partials additive: LDS merge, wave 0 epilogue.
__global__ __launch_bounds__(256, 6) void attn_mfma(
    const bf16_t* __restrict__ Qb, const bf16_t* __restrict__ Kb,
    const bf16_t* __restrict__ VT, bf16_t* __restrict__ ATTp) {
  __shared__ __align__(16) float smem[4352];      // 8KB staging / 17KB merge
  const int bh = blockIdx.x;
  const int pr = 63 - blockIdx.y;                 // long blocks first
  const int tid = threadIdx.x;
  const int wv = tid >> 6, lane = tid & 63;
  const int lr = lane & 15, quad = lane >> 4;
  const int q0 = pr * 32;
  const int mq = quad * 4;

  const bf16_t* Qbh = Qb + (long)bh * T_ * DP_;
  const bf16_t* Kbh = Kb + (long)bh * T_ * DP_;
  const bf16_t* VTbh = VT + (long)bh * DP_ * T_;

  const bf16x8 qf0 = *(const bf16x8*)(Qbh + (long)(q0 + lr) * DP_ + quad * 8);
  const bf16x8 qf1 = *(const bf16x8*)(Qbh + (long)(q0 + 16 + lr) * DP_ + quad * 8);

  f32x4 o00 = {0.f,0.f,0.f,0.f}, o01 = {0.f,0.f,0.f,0.f};
  f32x4 o10 = {0.f,0.f,0.f,0.f}, o11 = {0.f,0.f,0.f,0.f};
  bf16_t* pl0 = (bf16_t*)smem + wv * 1024;
  bf16_t* pl1 = pl0 + 512;
  const int rsw = ((lane ^ (lane >> 2)) << 3);    // reader swizzle offset

  bf16x8 kc0, kc1, vc0, vc1;
  if (wv <= pr) {
    const int kb = wv * 32;
    kc0 = *(const bf16x8*)(Kbh + (long)(kb + lr) * DP_ + quad * 8);
    kc1 = *(const bf16x8*)(Kbh + (long)(kb + 16 + lr) * DP_ + quad * 8);
    vc0 = *(const bf16x8*)(VTbh + (long)lr * T_ + kb + quad * 8);
    vc1 = *(const bf16x8*)(VTbh + (long)(16 + lr) * T_ + kb + quad * 8);
  }

  for (int t = wv; t <= pr; t += 4) {
    // ---- prefetch next tile's K/V ----
    bf16x8 kn0, kn1, vn0, vn1;
    const int tn = t + 4;
    if (tn <= pr) {
      const int kbn = tn * 32;
      kn0 = *(const bf16x8*)(Kbh + (long)(kbn + lr) * DP_ + quad * 8);
      kn1 = *(const bf16x8*)(Kbh + (long)(kbn + 16 + lr) * DP_ + quad * 8);
      vn0 = *(const bf16x8*)(VTbh + (long)lr * T_ + kbn + quad * 8);
      vn1 = *(const bf16x8*)(VTbh + (long)(16 + lr) * T_ + kbn + quad * 8);
    }

    f32x4 s00 = {0.f,0.f,0.f,0.f}, s01 = {0.f,0.f,0.f,0.f};
    f32x4 s10 = {0.f,0.f,0.f,0.f}, s11 = {0.f,0.f,0.f,0.f};
    s00 = __builtin_amdgcn_mfma_f32_16x16x32_bf16(qf0, kc0, s00, 0, 0, 0);
    s01 = __builtin_amdgcn_mfma_f32_16x16x32_bf16(qf0, kc1, s01, 0, 0, 0);
    s10 = __builtin_amdgcn_mfma_f32_16x16x32_bf16(qf1, kc0, s10, 0, 0, 0);
    s11 = __builtin_amdgcn_mfma_f32_16x16x32_bf16(qf1, kc1, s11, 0, 0, 0);

    if (t == pr) {   // diagonal superblock
#pragma unroll
      for (int r = 0; r < 4; ++r) {
        if (lr > mq + r) { s00[r] = -1e30f; s11[r] = -1e30f; }
        s01[r] = -1e30f;
      }
    }
#pragma unroll
    for (int r = 0; r < 4; ++r) {
      const float p00 = exp2f(s00[r]);
      const float p01 = exp2f(s01[r]);
      const float p10 = exp2f(s10[r]);
      const float p11 = exp2f(s11[r]);
      // A-frag block b = (k>>3)*16 + q; swizzled address b ^ (b>>2)
      const int b0 = ((lr >> 3) << 4) + mq + r;
      const int b1 = b0 + 32;
      const int i0 = ((b0 ^ (b0 >> 2)) << 3) + (lr & 7);
      const int i1 = ((b1 ^ (b1 >> 2)) << 3) + (lr & 7);
      pl0[i0] = (bf16_t)p00;
      pl0[i1] = (bf16_t)p01;
      pl1[i0] = (bf16_t)p10;
      pl1[i1] = (bf16_t)p11;
    }
    __builtin_amdgcn_wave_barrier();
    const bf16x8 pf0 = *(const bf16x8*)(pl0 + rsw);
    const bf16x8 pf1 = *(const bf16x8*)(pl1 + rsw);
    __builtin_amdgcn_wave_barrier();

    o00 = __builtin_amdgcn_mfma_f32_16x16x32_bf16(pf0, vc0, o00, 0, 0, 0);
    o01 = __builtin_amdgcn_mfma_f32_16x16x32_bf16(pf0, vc1, o01, 0, 0, 0);
    o10 = __builtin_amdgcn_mfma_f32_16x16x32_bf16(pf1, vc0, o10, 0, 0, 0);
    o11 = __builtin_amdgcn_mfma_f32_16x16x32_bf16(pf1, vc1, o11, 0, 0, 0);

    kc0 = kn0; kc1 = kn1; vc0 = vn0; vc1 = vn1;
  }

  // ---- merge: partials are additive (no-max softmax) ----
  __syncthreads();
  {
    float* my = smem + (wv * 64 + lane) * 17;     // stride 17: conflict-free
#pragma unroll
    for (int j = 0; j < 4; ++j) {
      my[j]      = o00[j];
      my[4 + j]  = o01[j];
      my[8 + j]  = o10[j];
      my[12 + j] = o11[j];
    }
  }
  __syncthreads();

  if (wv == 0) {
    float tot[16];
#pragma unroll
    for (int j = 0; j < 16; ++j)
      tot[j] = smem[lane * 17 + j] + smem[(64 + lane) * 17 + j] +
               smem[(128 + lane) * 17 + j] + smem[(192 + lane) * 17 + j];
    const int b = bh / H_, h = bh - b * H_;
#pragma unroll
    for (int r = 0; r < 4; ++r) {
      const float rl0 = 1.f / __shfl(tot[4 + r],  (lane & 48) + 5, 64);
      const float rl1 = 1.f / __shfl(tot[12 + r], (lane & 48) + 5, 64);
      const int qA = q0 + mq + r, qB = qA + 16;
      bf16_t* opA = ATTp + (long)(b * T_ + qA) * KP_ + h * D_;
      bf16_t* opB = ATTp + (long)(b * T_ + qB) * KP_ + h * D_;
      opA[lr] = (bf16_t)(tot[r] * rl0);
      opB[lr] = (bf16_t)(tot[8 + r] * rl1);
      if (lr < 5) {
        opA[16 + lr] = (bf16_t)(tot[4 + r] * rl0);
        opB[16 + lr] = (bf16_t)(tot[12 + r] * rl1);
      }
    }
  }
}

// ------------- out = ATT @ w_proj via MFMA --------------------------------
__global__ __launch_bounds__(256) void proj_mfma(
    const void* __restrict__ x, const bf16_t* __restrict__ ATTp,
    const bf16_t* __restrict__ WT, void* __restrict__ out) {
  __shared__ int sflag;
  probe_dtype(x, threadIdx.x, &sflag);
  const int isbf = sflag;

  const int m0 = blockIdx.x * 16;
  const int tid = threadIdx.x;
  const int wv = tid >> 6, lane = tid & 63;
  const int lr = lane & 15, quad = lane >> 4;

  const bf16x8* ap = (const bf16x8*)(ATTp + (long)(m0 + lr) * KP_ + quad * 8);
  const bf16x8 a0 = ap[0], a1 = ap[4], a2 = ap[8], a3 = ap[12];

  for (int nt = wv; nt < 8; nt += 4) {
    const int n0 = nt * 16;
    const bf16x8* bp = (const bf16x8*)(WT + (long)(n0 + lr) * KP_ + quad * 8);
    f32x4 acc = {0.f, 0.f, 0.f, 0.f};
    acc = __builtin_amdgcn_mfma_f32_16x16x32_bf16(a0, bp[0],  acc, 0, 0, 0);
    acc = __builtin_amdgcn_mfma_f32_16x16x32_bf16(a1, bp[4],  acc, 0, 0, 0);
    acc = __builtin_amdgcn_mfma_f32_16x16x32_bf16(a2, bp[8],  acc, 0, 0, 0);
    acc = __builtin_amdgcn_mfma_f32_16x16x32_bf16(a3, bp[12], acc, 0, 0, 0);

    const int c = n0 + lr;
    if (c < C_) {
#pragma unroll
      for (int r = 0; r < 4; ++r) {
        const int m = m0 + quad * 4 + r;
        if (isbf) stf((bf16*)out,  (long)m * C_ + c, acc[r]);
        else      stf((float*)out, (long)m * C_ + c, acc[r]);
      }
    }
  }
}

extern "C" void kernel_launch(void* const* d_in, const int* in_sizes, int n_in,
                              void* d_out, int out_size, void* d_ws, size_t ws_size,
                              hipStream_t stream) {
  const void* x      = d_in[0];
  const void* w_attn = d_in[1];
  const void* w_proj = d_in[2];

  char* base = (char*)d_ws;
  const long QKV = (long)48 * T_ * DP_;                    // 3,145,728 bf16 each
  bf16_t* Qb = (bf16_t*)(base + 256);
  bf16_t* Kb = Qb + QKV;
  bf16_t* VT = Kb + QKV;                                   // [bh][32][T]
  bf16_t* WTa  = VT + QKV;                                 // 384*128
  bf16_t* WTp  = WTa + 384 * KP_;                          // 128*128
  bf16_t* ATTp = WTp + KP_ * KP_;                          // 16384*128

  prep_w_kernel<<<64, 256, 0, stream>>>(x, w_attn, w_proj, WTa, WTp);
  qkv_mfma<<<M_ / 16, 256, 0, stream>>>(x, WTa, Qb, Kb, VT);
  attn_mfma<<<dim3(48, 64), 256, 0, stream>>>(Qb, Kb, VT, ATTp);
  proj_mfma<<<M_ / 16, 256, 0, stream>>>(x, ATTp, WTp, d_out);
}

// Round 11
// 135.441 us; speedup vs baseline: 1.2184x; 1.2184x over previous
//
#include <hip/hip_runtime.h>
#include <hip/hip_bf16.h>

// CausalSelfAttention: B=8 T=2048 C=126 H=6 D=21
// Round 11: R10's carried-register K/V prefetch spilled to scratch
// (WRITE_SIZE 11->69MB, VGPR 40). Replaced with PAIRED KEY-TILES: 64
// keys/iter, all 8 K/V loads issued in straight-line code at iteration
// top (no loop-carried vector state), one LDS round per 64 keys.
// launch_bounds(256,4) = 128 VGPR budget. qkv/proj/prep_w = R10.

#define B_ 8
#define T_ 2048
#define C_ 126
#define H_ 6
#define D_ 21
#define TC_ 378    // 3*C
#define KP_ 128    // padded GEMM inner dim
#define DP_ 32     // padded head dim
#define M_ 16384   // B*T
#define QSCALE 0.31481923469333463f   // (1/sqrt(21)) * log2(e)

typedef __hip_bfloat16 bf16;
typedef __bf16 bf16_t;
typedef __bf16 bf16x8 __attribute__((ext_vector_type(8)));
typedef float f32x4 __attribute__((ext_vector_type(4)));

__device__ __forceinline__ float ldf(const bf16* p, long i) { return __bfloat162float(p[i]); }
__device__ __forceinline__ float ldf(const float* p, long i) { return p[i]; }
__device__ __forceinline__ void stf(bf16* p, long i, float v) { p[i] = __float2bfloat16(v); }
__device__ __forceinline__ void stf(float* p, long i, float v) { p[i] = v; }

__device__ __forceinline__ unsigned int ld2(const bf16* x, long i) {
  return *(const unsigned int*)((const unsigned short*)x + i);
}
__device__ __forceinline__ unsigned int ld2(const float* x, long i) {
  const float2 f = *(const float2*)(x + i);
  union { bf16_t b[2]; unsigned int u; } cv;
  cv.b[0] = (bf16_t)f.x; cv.b[1] = (bf16_t)f.y;
  return cv.u;
}

// ------------- inline dtype probe: wave 0 -> sflag (1 = bf16) -------------
__device__ __forceinline__ void probe_dtype(const void* x, int tid, int* sflag) {
  if (tid < 64) {
    const unsigned int w = ((const unsigned int*)x)[tid * 97 + 13];
    const unsigned int e = (w >> 7) & 0xFF;
    const bool bflike = (e >= 115 && e <= 131) || ((w & 0x7FFFu) == 0);
    const unsigned long long mask = __ballot(bflike);
    if (tid == 0) *sflag = (__popcll(mask) >= 40) ? 1 : 0;
  }
  __syncthreads();
}

// ------------- prep: WT_attn[384][128], WT_proj[128][128] -----------------
template <typename T>
__device__ __forceinline__ void prep_w_body(const T* __restrict__ wa,
                                            const T* __restrict__ wp,
                                            bf16_t* __restrict__ WTa,
                                            bf16_t* __restrict__ WTp) {
  const int stride = gridDim.x * blockDim.x;
  const int idx0 = blockIdx.x * blockDim.x + threadIdx.x;
  for (int i = idx0; i < 384 * KP_ + KP_ * KP_; i += stride) {
    if (i < 384 * KP_) {
      const int n = i >> 7, k = i & 127;
      WTa[i] = (k < C_ && n < TC_) ? (bf16_t)ldf(wa, (long)k * TC_ + n) : (bf16_t)0.f;
    } else {
      const int j = i - 384 * KP_;
      const int n = j >> 7, k = j & 127;
      WTp[j] = (k < C_ && n < C_) ? (bf16_t)ldf(wp, (long)k * C_ + n) : (bf16_t)0.f;
    }
  }
}

__global__ __launch_bounds__(256) void prep_w_kernel(
    const void* __restrict__ x, const void* __restrict__ wa,
    const void* __restrict__ wp, bf16_t* __restrict__ WTa,
    bf16_t* __restrict__ WTp) {
  __shared__ int sflag;
  probe_dtype(x, threadIdx.x, &sflag);
  if (sflag) prep_w_body<bf16>((const bf16*)wa, (const bf16*)wp, WTa, WTp);
  else       prep_w_body<float>((const float*)wa, (const float*)wp, WTa, WTp);
}

// ------------- qkv = x @ w_attn via MFMA, LDS-transposed stores -----------
#define QS_ 40   // qbuf/kbuf d-stride (80 B, 16-aligned rows)

template <typename T>
__device__ __forceinline__ void qkv_body(
    const T* __restrict__ x, const bf16_t* __restrict__ WT,
    bf16_t* __restrict__ Qb, bf16_t* __restrict__ Kb, bf16_t* __restrict__ VT,
    bf16_t* __restrict__ xs, bf16_t* __restrict__ qbuf,
    bf16_t* __restrict__ kbuf, bf16_t* __restrict__ vbuf) {
  const int m0 = blockIdx.x * 16;
  const int tid = threadIdx.x;
  // packed x staging: 16 rows x 64 uint slots (128 cols, top 2 = pad)
  for (int i = tid; i < 16 * 64; i += 256) {
    const int row = i >> 6, cp = i & 63;
    unsigned int v = 0;
    if (cp < 63) v = ld2(x, (long)(m0 + row) * C_ + 2 * cp);
    ((unsigned int*)xs)[i] = v;
  }
  // pad init: qbuf/kbuf d=21..31 zero; vbuf d=21 ones, d=22..31 zero
  for (int i = tid; i < 6 * 16 * 11; i += 256) {
    const int h = i / 176, rem = i - h * 176, t = rem / 11, d = 21 + rem % 11;
    qbuf[(h * 16 + t) * QS_ + d] = (bf16_t)0.f;
    kbuf[(h * 16 + t) * QS_ + d] = (bf16_t)0.f;
  }
  for (int i = tid; i < 6 * 11 * 16; i += 256) {
    const int h = i / 176, rem = i - h * 176, d = 21 + rem / 16, t = rem % 16;
    vbuf[(h * 32 + d) * 16 + t] = (d == 21) ? (bf16_t)1.f : (bf16_t)0.f;
  }
  __syncthreads();

  const int wv = tid >> 6, lane = tid & 63;
  const int lr = lane & 15, quad = lane >> 4;
  const bf16_t* ar = xs + lr * KP_ + quad * 8;
  const bf16x8 a0 = *(const bf16x8*)(ar);
  const bf16x8 a1 = *(const bf16x8*)(ar + 32);
  const bf16x8 a2 = *(const bf16x8*)(ar + 64);
  const bf16x8 a3 = *(const bf16x8*)(ar + 96);

  for (int nt = wv; nt < 24; nt += 4) {
    const int n0 = nt * 16;
    const bf16x8* bp = (const bf16x8*)(WT + (long)(n0 + lr) * KP_ + quad * 8);
    f32x4 acc = {0.f, 0.f, 0.f, 0.f};
    acc = __builtin_amdgcn_mfma_f32_16x16x32_bf16(a0, bp[0],  acc, 0, 0, 0);
    acc = __builtin_amdgcn_mfma_f32_16x16x32_bf16(a1, bp[4],  acc, 0, 0, 0);
    acc = __builtin_amdgcn_mfma_f32_16x16x32_bf16(a2, bp[8],  acc, 0, 0, 0);
    acc = __builtin_amdgcn_mfma_f32_16x16x32_bf16(a3, bp[12], acc, 0, 0, 0);

    const int c = n0 + lr;                 // 0..383
    if (c < TC_) {
      const int which = c / C_;
      const int cc = c - which * C_;
      const int h = cc / D_, d = cc - h * D_;
#pragma unroll
      for (int r = 0; r < 4; ++r) {
        const int t = quad * 4 + r;        // C layout: row = quad*4 + reg
        if (which == 0)
          qbuf[(h * 16 + t) * QS_ + d] = (bf16_t)(acc[r] * QSCALE);  // incl log2e
        else if (which == 1)
          kbuf[(h * 16 + t) * QS_ + d] = (bf16_t)acc[r];
        else
          vbuf[(h * 32 + d) * 16 + t] = (bf16_t)acc[r];
      }
    }
  }
  __syncthreads();

  // ---- coalesced store phase ----
  const int b = m0 >> 11, t0 = m0 & 2047;
  for (int i = tid; i < 192; i += 256) {   // Q,K: 96 rows each, 64 B
    const int j = (i < 96) ? i : i - 96;
    const int h = j >> 4, t = j & 15;
    const int4* src = (const int4*)(((i < 96) ? qbuf : kbuf) + (h * 16 + t) * QS_);
    int4* dst = (int4*)((((i < 96) ? Qb : Kb)) + ((long)(b * H_ + h) * T_ + (t0 + t)) * DP_);
    dst[0] = src[0]; dst[1] = src[1]; dst[2] = src[2]; dst[3] = src[3];
  }
  for (int i = tid; i < 192; i += 256) {   // VT: 192 rows, 32 B
    const int h = i >> 5, d = i & 31;
    const int4* src = (const int4*)(vbuf + (h * 32 + d) * 16);
    int4* dst = (int4*)(VT + ((long)(b * H_ + h) * DP_ + d) * T_ + t0);
    dst[0] = src[0]; dst[1] = src[1];
  }
}

__global__ __launch_bounds__(256) void qkv_mfma(
    const void* __restrict__ x, const bf16_t* __restrict__ WT,
    bf16_t* __restrict__ Qb, bf16_t* __restrict__ Kb, bf16_t* __restrict__ VT) {
  __shared__ __align__(16) bf16_t xs[16 * KP_];
  __shared__ __align__(16) bf16_t qbuf[6 * 16 * QS_];
  __shared__ __align__(16) bf16_t kbuf[6 * 16 * QS_];
  __shared__ __align__(16) bf16_t vbuf[6 * 32 * 16];
  __shared__ int sflag;
  probe_dtype(x, threadIdx.x, &sflag);
  if (sflag) qkv_body<bf16>((const bf16*)x, WT, Qb, Kb, VT, xs, qbuf, kbuf, vbuf);
  else       qkv_body<float>((const float*)x, WT, Qb, Kb, VT, xs, qbuf, kbuf, vbuf);
}

// ------------- MFMA causal flash attention, paired key-tiles --------------
// grid (48, 64): x = bh (XCD-local), y -> pr = 63-y (long blocks first).
// Wave wv owns tiles {wv, wv+4, ...} <= pr, processed in PAIRS (t, t+4):
// 8 K/V loads issued up front (straight-line, no carried regs -> no spill),
// 8 S-MFMA, 32 exp2, one LDS round (4 regions x 512 bf16 per wave, XOR
// swizzle per region), 8 PV-MFMA. Odd count -> single-tile tail.
// Diagonal: pair body masks tile B iff t+4==pr (tile A never diagonal);
// tail masks iff t==pr. Q carries 1/sqrt(21)*log2e -> exp2f.
__global__ __launch_bounds__(256, 4) void attn_mfma(
    const bf16_t* __restrict__ Qb, const bf16_t* __restrict__ Kb,
    const bf16_t* __restrict__ VT, bf16_t* __restrict__ ATTp) {
  __shared__ __align__(16) float smem[4352];      // 16KB staging / 17KB merge
  const int bh = blockIdx.x;
  const int pr = 63 - blockIdx.y;                 // long blocks first
  const int tid = threadIdx.x;
  const int wv = tid >> 6, lane = tid & 63;
  const int lr = lane & 15, quad = lane >> 4;
  const int q0 = pr * 32;
  const int mq = quad * 4;

  const bf16_t* Qbh = Qb + (long)bh * T_ * DP_;
  const bf16_t* Kbh = Kb + (long)bh * T_ * DP_;
  const bf16_t* VTbh = VT + (long)bh * DP_ * T_;

  const bf16x8 qf0 = *(const bf16x8*)(Qbh + (long)(q0 + lr) * DP_ + quad * 8);
  const bf16x8 qf1 = *(const bf16x8*)(Qbh + (long)(q0 + 16 + lr) * DP_ + quad * 8);

  f32x4 o00 = {0.f,0.f,0.f,0.f}, o01 = {0.f,0.f,0.f,0.f};
  f32x4 o10 = {0.f,0.f,0.f,0.f}, o11 = {0.f,0.f,0.f,0.f};
  bf16_t* plA0 = (bf16_t*)smem + wv * 2048;
  bf16_t* plA1 = plA0 + 512;
  bf16_t* plB0 = plA0 + 1024;
  bf16_t* plB1 = plA0 + 1536;
  const int rsw = ((lane ^ (lane >> 2)) << 3);    // reader swizzle offset
  // writer swizzle indices (same for every tile region)
  const int wb0 = ((lr >> 3) << 4) + mq;          // + r, keys 0..15
  // store helper index: i = ((b ^ (b>>2)) << 3) + (lr & 7)

  int t = wv;
  for (; t + 4 <= pr; t += 8) {
    const int kbA = t * 32, kbB = (t + 4) * 32;
    const bf16x8 kA0 = *(const bf16x8*)(Kbh + (long)(kbA + lr) * DP_ + quad * 8);
    const bf16x8 kA1 = *(const bf16x8*)(Kbh + (long)(kbA + 16 + lr) * DP_ + quad * 8);
    const bf16x8 kB0 = *(const bf16x8*)(Kbh + (long)(kbB + lr) * DP_ + quad * 8);
    const bf16x8 kB1 = *(const bf16x8*)(Kbh + (long)(kbB + 16 + lr) * DP_ + quad * 8);
    const bf16x8 vA0 = *(const bf16x8*)(VTbh + (long)lr * T_ + kbA + quad * 8);
    const bf16x8 vA1 = *(const bf16x8*)(VTbh + (long)(16 + lr) * T_ + kbA + quad * 8);
    const bf16x8 vB0 = *(const bf16x8*)(VTbh + (long)lr * T_ + kbB + quad * 8);
    const bf16x8 vB1 = *(const bf16x8*)(VTbh + (long)(16 + lr) * T_ + kbB + quad * 8);

    f32x4 sA00 = {0.f,0.f,0.f,0.f}, sA01 = {0.f,0.f,0.f,0.f};
    f32x4 sA10 = {0.f,0.f,0.f,0.f}, sA11 = {0.f,0.f,0.f,0.f};
    f32x4 sB00 = {0.f,0.f,0.f,0.f}, sB01 = {0.f,0.f,0.f,0.f};
    f32x4 sB10 = {0.f,0.f,0.f,0.f}, sB11 = {0.f,0.f,0.f,0.f};
    sA00 = __builtin_amdgcn_mfma_f32_16x16x32_bf16(qf0, kA0, sA00, 0, 0, 0);
    sA01 = __builtin_amdgcn_mfma_f32_16x16x32_bf16(qf0, kA1, sA01, 0, 0, 0);
    sA10 = __builtin_amdgcn_mfma_f32_16x16x32_bf16(qf1, kA0, sA10, 0, 0, 0);
    sA11 = __builtin_amdgcn_mfma_f32_16x16x32_bf16(qf1, kA1, sA11, 0, 0, 0);
    sB00 = __builtin_amdgcn_mfma_f32_16x16x32_bf16(qf0, kB0, sB00, 0, 0, 0);
    sB01 = __builtin_amdgcn_mfma_f32_16x16x32_bf16(qf0, kB1, sB01, 0, 0, 0);
    sB10 = __builtin_amdgcn_mfma_f32_16x16x32_bf16(qf1, kB0, sB10, 0, 0, 0);
    sB11 = __builtin_amdgcn_mfma_f32_16x16x32_bf16(qf1, kB1, sB11, 0, 0, 0);

    if (t + 4 == pr) {   // tile B is the diagonal superblock
#pragma unroll
      for (int r = 0; r < 4; ++r) {
        if (lr > mq + r) { sB00[r] = -1e30f; sB11[r] = -1e30f; }
        sB01[r] = -1e30f;
      }
    }
#pragma unroll
    for (int r = 0; r < 4; ++r) {
      const int b0 = wb0 + r, b1 = b0 + 32;
      const int i0 = ((b0 ^ (b0 >> 2)) << 3) + (lr & 7);
      const int i1 = ((b1 ^ (b1 >> 2)) << 3) + (lr & 7);
      plA0[i0] = (bf16_t)exp2f(sA00[r]);
      plA0[i1] = (bf16_t)exp2f(sA01[r]);
      plA1[i0] = (bf16_t)exp2f(sA10[r]);
      plA1[i1] = (bf16_t)exp2f(sA11[r]);
      plB0[i0] = (bf16_t)exp2f(sB00[r]);
      plB0[i1] = (bf16_t)exp2f(sB01[r]);
      plB1[i0] = (bf16_t)exp2f(sB10[r]);
      plB1[i1] = (bf16_t)exp2f(sB11[r]);
    }
    __builtin_amdgcn_wave_barrier();
    const bf16x8 pfA0 = *(const bf16x8*)(plA0 + rsw);
    const bf16x8 pfA1 = *(const bf16x8*)(plA1 + rsw);
    const bf16x8 pfB0 = *(const bf16x8*)(plB0 + rsw);
    const bf16x8 pfB1 = *(const bf16x8*)(plB1 + rsw);
    __builtin_amdgcn_wave_barrier();

    o00 = __builtin_amdgcn_mfma_f32_16x16x32_bf16(pfA0, vA0, o00, 0, 0, 0);
    o01 = __builtin_amdgcn_mfma_f32_16x16x32_bf16(pfA0, vA1, o01, 0, 0, 0);
    o10 = __builtin_amdgcn_mfma_f32_16x16x32_bf16(pfA1, vA0, o10, 0, 0, 0);
    o11 = __builtin_amdgcn_mfma_f32_16x16x32_bf16(pfA1, vA1, o11, 0, 0, 0);
    o00 = __builtin_amdgcn_mfma_f32_16x16x32_bf16(pfB0, vB0, o00, 0, 0, 0);
    o01 = __builtin_amdgcn_mfma_f32_16x16x32_bf16(pfB0, vB1, o01, 0, 0, 0);
    o10 = __builtin_amdgcn_mfma_f32_16x16x32_bf16(pfB1, vB0, o10, 0, 0, 0);
    o11 = __builtin_amdgcn_mfma_f32_16x16x32_bf16(pfB1, vB1, o11, 0, 0, 0);
  }

  if (t <= pr) {        // single-tile tail
    const int kb = t * 32;
    const bf16x8 k0 = *(const bf16x8*)(Kbh + (long)(kb + lr) * DP_ + quad * 8);
    const bf16x8 k1 = *(const bf16x8*)(Kbh + (long)(kb + 16 + lr) * DP_ + quad * 8);
    const bf16x8 v0 = *(const bf16x8*)(VTbh + (long)lr * T_ + kb + quad * 8);
    const bf16x8 v1 = *(const bf16x8*)(VTbh + (long)(16 + lr) * T_ + kb + quad * 8);
    f32x4 s00 = {0.f,0.f,0.f,0.f}, s01 = {0.f,0.f,0.f,0.f};
    f32x4 s10 = {0.f,0.f,0.f,0.f}, s11 = {0.f,0.f,0.f,0.f};
    s00 = __builtin_amdgcn_mfma_f32_16x16x32_bf16(qf0, k0, s00, 0, 0, 0);
    s01 = __builtin_amdgcn_mfma_f32_16x16x32_bf16(qf0, k1, s01, 0, 0, 0);
    s10 = __builtin_amdgcn_mfma_f32_16x16x32_bf16(qf1, k0, s10, 0, 0, 0);
    s11 = __builtin_amdgcn_mfma_f32_16x16x32_bf16(qf1, k1, s11, 0, 0, 0);
    if (t == pr) {
#pragma unroll
      for (int r = 0; r < 4; ++r) {
        if (lr > mq + r) { s00[r] = -1e30f; s11[r] = -1e30f; }
        s01[r] = -1e30f;
      }
    }
#pragma unroll
    for (int r = 0; r < 4; ++r) {
      const int b0 = wb0 + r, b1 = b0 + 32;
      const int i0 = ((b0 ^ (b0 >> 2)) << 3) + (lr & 7);
      const int i1 = ((b1 ^ (b1 >> 2)) << 3) + (lr & 7);
      plA0[i0] = (bf16_t)exp2f(s00[r]);
      plA0[i1] = (bf16_t)exp2f(s01[r]);
      plA1[i0] = (bf16_t)exp2f(s10[r]);
      plA1[i1] = (bf16_t)exp2f(s11[r]);
    }
    __builtin_amdgcn_wave_barrier();
    const bf16x8 pf0 = *(const bf16x8*)(plA0 + rsw);
    const bf16x8 pf1 = *(const bf16x8*)(plA1 + rsw);
    __builtin_amdgcn_wave_barrier();
    o00 = __builtin_amdgcn_mfma_f32_16x16x32_bf16(pf0, v0, o00, 0, 0, 0);
    o01 = __builtin_amdgcn_mfma_f32_16x16x32_bf16(pf0, v1, o01, 0, 0, 0);
    o10 = __builtin_amdgcn_mfma_f32_16x16x32_bf16(pf1, v0, o10, 0, 0, 0);
    o11 = __builtin_amdgcn_mfma_f32_16x16x32_bf16(pf1, v1, o11, 0, 0, 0);
  }

  // ---- merge: partials are additive (no-max softmax) ----
  __syncthreads();
  {
    float* my = smem + (wv * 64 + lane) * 17;     // stride 17: conflict-free
#pragma unroll
    for (int j = 0; j < 4; ++j) {
      my[j]      = o00[j];
      my[4 + j]  = o01[j];
      my[8 + j]  = o10[j];
      my[12 + j] = o11[j];
    }
  }
  __syncthreads();

  if (wv == 0) {
    float tot[16];
#pragma unroll
    for (int j = 0; j < 16; ++j)
      tot[j] = smem[lane * 17 + j] + smem[(64 + lane) * 17 + j] +
               smem[(128 + lane) * 17 + j] + smem[(192 + lane) * 17 + j];
    const int b = bh / H_, h = bh - b * H_;
#pragma unroll
    for (int r = 0; r < 4; ++r) {
      const float rl0 = 1.f / __shfl(tot[4 + r],  (lane & 48) + 5, 64);
      const float rl1 = 1.f / __shfl(tot[12 + r], (lane & 48) + 5, 64);
      const int qA = q0 + mq + r, qB = qA + 16;
      bf16_t* opA = ATTp + (long)(b * T_ + qA) * KP_ + h * D_;
      bf16_t* opB = ATTp + (long)(b * T_ + qB) * KP_ + h * D_;
      opA[lr] = (bf16_t)(tot[r] * rl0);
      opB[lr] = (bf16_t)(tot[8 + r] * rl1);
      if (lr < 5) {
        opA[16 + lr] = (bf16_t)(tot[4 + r] * rl0);
        opB[16 + lr] = (bf16_t)(tot[12 + r] * rl1);
      }
    }
  }
}

// ------------- out = ATT @ w_proj via MFMA --------------------------------
__global__ __launch_bounds__(256) void proj_mfma(
    const void* __restrict__ x, const bf16_t* __restrict__ ATTp,
    const bf16_t* __restrict__ WT, void* __restrict__ out) {
  __shared__ int sflag;
  probe_dtype(x, threadIdx.x, &sflag);
  const int isbf = sflag;

  const int m0 = blockIdx.x * 16;
  const int tid = threadIdx.x;
  const int wv = tid >> 6, lane = tid & 63;
  const int lr = lane & 15, quad = lane >> 4;

  const bf16x8* ap = (const bf16x8*)(ATTp + (long)(m0 + lr) * KP_ + quad * 8);
  const bf16x8 a0 = ap[0], a1 = ap[4], a2 = ap[8], a3 = ap[12];

  for (int nt = wv; nt < 8; nt += 4) {
    const int n0 = nt * 16;
    const bf16x8* bp = (const bf16x8*)(WT + (long)(n0 + lr) * KP_ + quad * 8);
    f32x4 acc = {0.f, 0.f, 0.f, 0.f};
    acc = __builtin_amdgcn_mfma_f32_16x16x32_bf16(a0, bp[0],  acc, 0, 0, 0);
    acc = __builtin_amdgcn_mfma_f32_16x16x32_bf16(a1, bp[4],  acc, 0, 0, 0);
    acc = __builtin_amdgcn_mfma_f32_16x16x32_bf16(a2, bp[8],  acc, 0, 0, 0);
    acc = __builtin_amdgcn_mfma_f32_16x16x32_bf16(a3, bp[12], acc, 0, 0, 0);

    const int c = n0 + lr;
    if (c < C_) {
#pragma unroll
      for (int r = 0; r < 4; ++r) {
        const int m = m0 + quad * 4 + r;
        if (isbf) stf((bf16*)out,  (long)m * C_ + c, acc[r]);
        else      stf((float*)out, (long)m * C_ + c, acc[r]);
      }
    }
  }
}

extern "C" void kernel_launch(void* const* d_in, const int* in_sizes, int n_in,
                              void* d_out, int out_size, void* d_ws, size_t ws_size,
                              hipStream_t stream) {
  const void* x      = d_in[0];
  const void* w_attn = d_in[1];
  const void* w_proj = d_in[2];

  char* base = (char*)d_ws;
  const long QKV = (long)48 * T_ * DP_;                    // 3,145,728 bf16 each
  bf16_t* Qb = (bf16_t*)(base + 256);
  bf16_t* Kb = Qb + QKV;
  bf16_t* VT = Kb + QKV;                                   // [bh][32][T]
  bf16_t* WTa  = VT + QKV;                                 // 384*128
  bf16_t* WTp  = WTa + 384 * KP_;                          // 128*128
  bf16_t* ATTp = WTp + KP_ * KP_;                          // 16384*128

  prep_w_kernel<<<64, 256, 0, stream>>>(x, w_attn, w_proj, WTa, WTp);
  qkv_mfma<<<M_ / 16, 256, 0, stream>>>(x, WTa, Qb, Kb, VT);
  attn_mfma<<<dim3(48, 64), 256, 0, stream>>>(Qb, Kb, VT, ATTp);
  proj_mfma<<<M_ / 16, 256, 0, stream>>>(x, ATTp, WTp, d_out);
}